// Round 17
// baseline (229.626 us; speedup 1.0000x reference)
//
#include <hip/hip_runtime.h>
#include <hip/hip_bf16.h>
#include <hip/hip_fp16.h>

// GCN 3-layer: out = A_hat @ (A_hat @ relu(A_hat @ relu(X W1)+b1 ... ) )
// R2-R16: vectorized agg, W-LDS fdot2 GEMM (BR=64), f16 activations, 4B edge
//         records, norm factorized into GEMM epilogue, fused prelude +
//         single-launch lookback scan, fill+gemm1 range-split fusion,
//         cursor pre-seeded with offsets (1 random atomic per edge).
// R17: (a) agg = ONE DEST PER WAVE with HALF-WAVE EDGE SPLIT — lanes 0-31
//      gather even edges (full 256B row, 8B/lane preserved), lanes 32-63 odd;
//      4-shfl cross-half reduce. Trip count ceil(deg/2), uniform to +-1 edge
//      (kills the max(degA,degB) pairing waste AND halves the serial chain —
//      what R9's 4B-gather variant got wrong).
//      (b) x->f16 convert fused into count_edges via block-range split.

typedef _Float16 h2 __attribute__((ext_vector_type(2)));
typedef _Float16 h8 __attribute__((ext_vector_type(8)));

__device__ inline float4 h4_to_f4(float2 raw) {
    __half2 lo = *reinterpret_cast<__half2*>(&raw.x);
    __half2 hi = *reinterpret_cast<__half2*>(&raw.y);
    float2 a = __half22float2(lo);
    float2 b = __half22float2(hi);
    return make_float4(a.x, a.y, b.x, b.y);
}

__device__ inline uint pack_h2(float a, float b) {
    __half2 h = __floats2half2_rn(a, b);
    return *reinterpret_cast<uint*>(&h);
}

// Prelude: zero counts, init scan aggregate slots to -1 (small grid now).
__global__ __launch_bounds__(256) void prelude_init_kernel(int4* __restrict__ counts4, int n4,
                                                           int* __restrict__ aggslot, int nb) {
    int i = blockIdx.x * 256 + threadIdx.x;
    if (i < n4) counts4[i] = make_int4(0, 0, 0, 0);
    if (i < nb) aggslot[i] = -1;
}

// R17b: count edges (blocks [0,CB)) + x->f16 convert (blocks [CB, CB+XB)).
// Independent streaming tasks; convert hides under count's atomic latency.
__global__ __launch_bounds__(256) void count_convert_kernel(const int* __restrict__ col,
                                                            int* __restrict__ counts, int E, int CB,
                                                            const float4* __restrict__ x,
                                                            uint2* __restrict__ x16, int xc4) {
    int b = blockIdx.x;
    if (b < CB) {
        int e = b * 256 + threadIdx.x;
        if (e < E) atomicAdd(&counts[col[e]], 1);
    } else {
        int i = (b - CB) * 256 + threadIdx.x;
        if (i < xc4) {
            float4 v = x[i];
            x16[i] = make_uint2(pack_h2(v.x, v.y), pack_h2(v.z, v.w));
        }
    }
}

// Single-launch scan (lookback): publish aggregate, then poll predecessors.
// cursor[i] seeded with offsets[i] so fill needs no offsets read.
__global__ __launch_bounds__(256) void scan_fused_kernel(const int* __restrict__ counts,
                                                         int* __restrict__ aggslot,
                                                         int* __restrict__ offsets,
                                                         int* __restrict__ cursor,
                                                         float* __restrict__ dinv, int n) {
    int b = blockIdx.x;
    int tid = threadIdx.x;
    int lane = tid & 63, wid = tid >> 6;
    int i = b * 256 + tid;
    int c = (i < n) ? counts[i] : 0;

    int s = c;
    #pragma unroll
    for (int d = 1; d < 64; d <<= 1) {
        int u = __shfl_up(s, d);
        if (lane >= d) s += u;
    }
    __shared__ int ws[4];
    if (lane == 63) ws[wid] = s;
    __syncthreads();
    int add = 0;
    for (int w = 0; w < wid; ++w) add += ws[w];
    int incl = s + add;
    int blocktotal = ws[0] + ws[1] + ws[2] + ws[3];
    __syncthreads();

    if (tid == 0) atomicExch(&aggslot[b], blocktotal);

    int pre = 0;
    for (int t = tid; t < b; t += 256) {
        int a;
        do { a = atomicAdd(&aggslot[t], 0); } while (a < 0);
        pre += a;
    }
    #pragma unroll
    for (int d = 1; d < 64; d <<= 1) pre += __shfl_xor(pre, d);
    if (lane == 0) ws[wid] = pre;
    __syncthreads();
    int blockoff = ws[0] + ws[1] + ws[2] + ws[3];

    if (i < n) {
        int o = blockoff + incl - c;
        offsets[i] = o;
        cursor[i] = o;                         // seed with offset
        dinv[i] = rsqrtf((float)(c + 1));      // +1 self loop
    }
    if (i == n - 1) offsets[n] = blockoff + incl;
}

// GEMM tile body: 64 rows x DO cols, fdot2, f32 acc, dinv-scaled f16 store.
template <int DO>
__device__ __forceinline__ void gemm_tile_body(int tileb,
                                               const __half* __restrict__ A,
                                               const float* __restrict__ W,
                                               const float* __restrict__ dinv,
                                               __half* __restrict__ out, int n,
                                               h2* Wl) {
    constexpr int K = 128;
    constexpr int COLTH = DO / 8;          // 16 (DO=128) or 8 (DO=64)
    constexpr int ROWTH = 256 / COLTH;     // 16 or 32
    constexpr int R = 64 / ROWTH;          // 4 (DO=128) or 2 (DO=64)
    constexpr int BR = ROWTH * R;          // 64 rows per block
    constexpr int HALF = DO / 2;

    int tid = threadIdx.x;
    for (int idx = tid; idx < (K / 2) * (DO / 4); idx += 256) {
        int k2 = idx / (DO / 4);
        int c4 = idx % (DO / 4);
        float4 w0 = ((const float4*)(W + (size_t)(2 * k2) * DO))[c4];
        float4 w1 = ((const float4*)(W + (size_t)(2 * k2 + 1) * DO))[c4];
        h2* dst = &Wl[k2 * DO + c4 * 4];
        h2 d0; d0.x = (_Float16)w0.x; d0.y = (_Float16)w1.x; dst[0] = d0;
        h2 d1; d1.x = (_Float16)w0.y; d1.y = (_Float16)w1.y; dst[1] = d1;
        h2 d2; d2.x = (_Float16)w0.z; d2.y = (_Float16)w1.z; dst[2] = d2;
        h2 d3; d3.x = (_Float16)w0.w; d3.y = (_Float16)w1.w; dst[3] = d3;
    }
    __syncthreads();

    int ct = tid % COLTH;
    int rt = tid / COLTH;
    int rb = tileb * BR + rt * R;

    int rowc[R];
    #pragma unroll
    for (int i = 0; i < R; ++i) {
        int row = rb + i;
        rowc[i] = (row < n) ? row : (n - 1);
    }

    float acc[R][8];
    #pragma unroll
    for (int i = 0; i < R; ++i)
        #pragma unroll
        for (int c = 0; c < 8; ++c) acc[i][c] = 0.f;

    #pragma unroll 2
    for (int k8 = 0; k8 < K / 8; ++k8) {
        h8 av[R];
        #pragma unroll
        for (int i = 0; i < R; ++i) {
            av[i] = ((const h8*)(A + (size_t)rowc[i] * K))[k8];
        }
        #pragma unroll
        for (int kk = 0; kk < 4; ++kk) {
            int k2 = k8 * 4 + kk;
            h2 w0[4], w1[4];
            *(uint4*)w0 = *(const uint4*)(&Wl[k2 * DO + ct * 4]);
            *(uint4*)w1 = *(const uint4*)(&Wl[k2 * DO + HALF + ct * 4]);
            #pragma unroll
            for (int i = 0; i < R; ++i) {
                h2 a; a.x = av[i][2 * kk]; a.y = av[i][2 * kk + 1];
                #pragma unroll
                for (int c = 0; c < 4; ++c) {
                    acc[i][c]     = __builtin_amdgcn_fdot2(a, w0[c], acc[i][c], false);
                    acc[i][4 + c] = __builtin_amdgcn_fdot2(a, w1[c], acc[i][4 + c], false);
                }
            }
        }
    }

    #pragma unroll
    for (int i = 0; i < R; ++i) {
        int row = rb + i;
        if (row < n) {
            float dv = dinv[row];
            uint2 q0 = make_uint2(pack_h2(acc[i][0] * dv, acc[i][1] * dv),
                                  pack_h2(acc[i][2] * dv, acc[i][3] * dv));
            uint2 q1 = make_uint2(pack_h2(acc[i][4] * dv, acc[i][5] * dv),
                                  pack_h2(acc[i][6] * dv, acc[i][7] * dv));
            *(uint2*)(out + (size_t)row * DO + ct * 4) = q0;
            *(uint2*)(out + (size_t)row * DO + HALF + ct * 4) = q1;
        }
    }
}

// Plain GEMM kernel (layers 2/3).
template <int DO>
__global__ __launch_bounds__(256) void gemm16_kernel(const __half* __restrict__ A,
                                                     const float* __restrict__ W,
                                                     const float* __restrict__ dinv,
                                                     __half* __restrict__ out, int n) {
    constexpr int K = 128;
    __shared__ alignas(16) h2 Wl[(K / 2) * DO];
    gemm_tile_body<DO>(blockIdx.x, A, W, dinv, out, n, Wl);
}

// Range-split fill + gemm1 (R13-measured best). Blocks [0,FB): fill edges
// (one atomic per edge, cursor pre-seeded). Blocks [FB,FB+GB): gemm tiles.
__global__ __launch_bounds__(256) void fill_gemm1_kernel(const int* __restrict__ row,
                                                         const int* __restrict__ col,
                                                         int* __restrict__ cursor,
                                                         int* __restrict__ srcs, int E, int FB,
                                                         const __half* __restrict__ A,
                                                         const float* __restrict__ W,
                                                         const float* __restrict__ dinv,
                                                         __half* __restrict__ out, int n) {
    __shared__ alignas(16) h2 Wl[64 * 128];   // 32 KB (DO=128 geometry)
    int b = blockIdx.x;
    if (b < FB) {
        int e = b * 256 + threadIdx.x;
        if (e < E) {
            int c = col[e];
            int pos = atomicAdd(&cursor[c], 1);
            srcs[pos] = row[e];
        }
    } else {
        gemm_tile_body<128>(b - FB, A, W, dinv, out, n, Wl);
    }
}

// out[d] = bias + dinv[d] * (hw_s[d] + sum_e hw_s[src(e)])   (f32 acc)
// R17a: ONE DEST PER WAVE, edge list split across GROUPS lane-groups
// (DO=128: 2 half-waves of 32 lanes; DO=64: 4 groups of 16). Each group
// gathers every-GROUPS-th edge's full row (8B/lane), then shfl_xor reduce.
template <int DO, bool RELU, bool F16OUT>
__global__ __launch_bounds__(256) void agg_kernel(const __half* __restrict__ hw,
                                                  const int* __restrict__ offsets,
                                                  const int* __restrict__ srcs,
                                                  const float* __restrict__ dinv,
                                                  const float* __restrict__ bias,
                                                  void* __restrict__ outp, int n) {
    constexpr int TPD = DO / 4;            // lanes covering one row (32 or 16)
    constexpr int GROUPS = 64 / TPD;       // edge stride (2 or 4)
    int wv = threadIdx.x >> 6;
    int lane = threadIdx.x & 63;
    int d = blockIdx.x * 4 + wv;
    if (d >= n) return;

    int g = lane / TPD;                    // edge-group of this lane
    int j = lane % TPD;                    // 4-col chunk index

    const float2* hw2 = (const float2*)hw;
    int beg = offsets[d];
    int end = offsets[d + 1];

    float4 acc = make_float4(0.f, 0.f, 0.f, 0.f);
    if (g == 0) acc = h4_to_f4(hw2[(size_t)d * TPD + j]);   // self term once

    int e = beg + g;
    // 4-deep batch per group (4 independent gathers in flight), stride GROUPS
    for (; e + 3 * GROUPS < end; e += 4 * GROUPS) {
        int s0 = srcs[e];
        int s1 = srcs[e + GROUPS];
        int s2 = srcs[e + 2 * GROUPS];
        int s3 = srcs[e + 3 * GROUPS];
        float4 v0 = h4_to_f4(hw2[(size_t)s0 * TPD + j]);
        float4 v1 = h4_to_f4(hw2[(size_t)s1 * TPD + j]);
        float4 v2 = h4_to_f4(hw2[(size_t)s2 * TPD + j]);
        float4 v3 = h4_to_f4(hw2[(size_t)s3 * TPD + j]);
        acc.x += v0.x; acc.y += v0.y; acc.z += v0.z; acc.w += v0.w;
        acc.x += v1.x; acc.y += v1.y; acc.z += v1.z; acc.w += v1.w;
        acc.x += v2.x; acc.y += v2.y; acc.z += v2.z; acc.w += v2.w;
        acc.x += v3.x; acc.y += v3.y; acc.z += v3.z; acc.w += v3.w;
    }
    for (; e < end; e += GROUPS) {
        float4 v = h4_to_f4(hw2[(size_t)srcs[e] * TPD + j]);
        acc.x += v.x; acc.y += v.y; acc.z += v.z; acc.w += v.w;
    }

    // reduce partial sums across groups (lane-chunk xor)
    #pragma unroll
    for (int off = TPD; off < 64; off <<= 1) {
        acc.x += __shfl_xor(acc.x, off);
        acc.y += __shfl_xor(acc.y, off);
        acc.z += __shfl_xor(acc.z, off);
        acc.w += __shfl_xor(acc.w, off);
    }

    if (g == 0) {
        float di = dinv[d];
        float4 b4 = ((const float4*)bias)[j];
        acc.x = b4.x + di * acc.x;
        acc.y = b4.y + di * acc.y;
        acc.z = b4.z + di * acc.z;
        acc.w = b4.w + di * acc.w;
        if (RELU) {
            acc.x = fmaxf(acc.x, 0.f); acc.y = fmaxf(acc.y, 0.f);
            acc.z = fmaxf(acc.z, 0.f); acc.w = fmaxf(acc.w, 0.f);
        }
        if (F16OUT) {
            uint2 q = make_uint2(pack_h2(acc.x, acc.y), pack_h2(acc.z, acc.w));
            ((uint2*)outp)[(size_t)d * TPD + j] = q;
        } else {
            ((float4*)outp)[(size_t)d * TPD + j] = acc;
        }
    }
}

extern "C" void kernel_launch(void* const* d_in, const int* in_sizes, int n_in,
                              void* d_out, int out_size, void* d_ws, size_t ws_size,
                              hipStream_t stream) {
    const float* x  = (const float*)d_in[0];
    const float* W1 = (const float*)d_in[1];
    const float* b1 = (const float*)d_in[2];
    const float* W2 = (const float*)d_in[3];
    const float* b2 = (const float*)d_in[4];
    const float* W3 = (const float*)d_in[5];
    const float* b3 = (const float*)d_in[6];
    const int*   ei = (const int*)d_in[7];

    const int N = in_sizes[0] / 128;
    const int E = in_sizes[7] / 2;
    const int* rowi = ei;       // edge_index[0] = sources
    const int* coli = ei + E;   // edge_index[1] = targets

    float* out = (float*)d_out;

    // workspace carve-up (256B aligned)
    char* ws = (char*)d_ws;
    size_t off = 0;
    auto alloc = [&](size_t bytes) -> void* {
        void* p = ws + off;
        off = (off + bytes + 255) & ~(size_t)255;
        return p;
    };
    const int NB = (N + 255) / 256;        // scan blocks (196 for N=50000)
    float* dinv     = (float*)alloc((size_t)N * 4);
    int*   counts   = (int*)  alloc(((size_t)N + 4) * 4);  // int4-padded
    int*   offsets  = (int*)  alloc((size_t)(N + 1) * 4);
    int*   cursor   = (int*)  alloc((size_t)N * 4);
    int*   aggslot  = (int*)  alloc((size_t)NB * 4);
    int*   srcs     = (int*)  alloc((size_t)E * 4);
    __half* x16     = (__half*)alloc((size_t)N * 128 * 2);
    __half* hw16    = (__half*)alloc((size_t)N * 128 * 2);
    __half* h16     = (__half*)alloc((size_t)N * 128 * 2);

    // ---- prelude (zero counts + slots), then fused count+convert ----
    const int n4 = (N + 3) / 4;
    const int xc4 = N * 128 / 4;
    int pre_elems = (n4 > NB) ? n4 : NB;
    prelude_init_kernel<<<(pre_elems + 255) / 256, 256, 0, stream>>>((int4*)counts, n4, aggslot, NB);
    const int CB = (E + 255) / 256;
    const int XB = (xc4 + 255) / 256;
    count_convert_kernel<<<CB + XB, 256, 0, stream>>>(coli, counts, E, CB,
                                                      (const float4*)x, (uint2*)x16, xc4);
    scan_fused_kernel<<<NB, 256, 0, stream>>>(counts, aggslot, offsets, cursor, dinv, N);

    // ---- fused fill_csr + layer-1 GEMM (range-split) ----
    const int FB = (E + 255) / 256;            // fill blocks (2344)
    const int GB = (N + 63) / 64;              // gemm tiles (782)
    fill_gemm1_kernel<<<FB + GB, 256, 0, stream>>>(rowi, coli, cursor, srcs, E, FB,
                                                   x16, W1, dinv, hw16, N);
    agg_kernel<128, true, true><<<(N + 3) / 4, 256, 0, stream>>>(hw16, offsets, srcs, dinv, b1, h16, N);

    // ---- layer 2 ----
    gemm16_kernel<128><<<(N + 63) / 64, 256, 0, stream>>>(h16, W2, dinv, hw16, N);
    agg_kernel<128, true, true><<<(N + 3) / 4, 256, 0, stream>>>(hw16, offsets, srcs, dinv, b2, h16, N);

    // ---- layer 3 (no relu), width 64, f32 out ----
    gemm16_kernel<64><<<(N + 63) / 64, 256, 0, stream>>>(h16, W3, dinv, hw16, N);
    agg_kernel<64, false, false><<<(N + 3) / 4, 256, 0, stream>>>(hw16, offsets, srcs, dinv, b3, out, N);
}

// Round 18
// 206.794 us; speedup vs baseline: 1.1104x; 1.1104x over previous
//
#include <hip/hip_runtime.h>
#include <hip/hip_bf16.h>
#include <hip/hip_fp16.h>

// GCN 3-layer: out = A_hat @ (A_hat @ relu(A_hat @ relu(X W1)+b1 ... ) )
// FINAL (R18) = exact revert to R13, the measured-best configuration (206.8us):
//   - f16 activations/gather table, f32 accumulation everywhere
//   - norm factorized: rows pre-scaled by dinv[row] in GEMM epilogue
//   - 4B edge records (src only)
//   - fused prelude (zero+slots+x->f16 in one pass over x)
//   - single-launch lookback scan (publish-then-poll)
//   - fill_csr + layer-1 GEMM fused, range-split
//   - TPD=32 agg with software-pipelined srcs loads
// R14-R17 alternatives (modulo interleave, cursor-seed, half-wave agg split,
// count+convert fusion) all measured worse; reverted.

typedef _Float16 h2 __attribute__((ext_vector_type(2)));
typedef _Float16 h8 __attribute__((ext_vector_type(8)));

__device__ inline float4 h4_to_f4(float2 raw) {
    __half2 lo = *reinterpret_cast<__half2*>(&raw.x);
    __half2 hi = *reinterpret_cast<__half2*>(&raw.y);
    float2 a = __half22float2(lo);
    float2 b = __half22float2(hi);
    return make_float4(a.x, a.y, b.x, b.y);
}

__device__ inline uint pack_h2(float a, float b) {
    __half2 h = __floats2half2_rn(a, b);
    return *reinterpret_cast<uint*>(&h);
}

// Fused prelude: zero counts, init scan aggregate slots to -1, convert x->f16.
__global__ __launch_bounds__(256) void prelude_init_kernel(const float4* __restrict__ x,
                                                           uint2* __restrict__ x16,
                                                           int4* __restrict__ counts4, int n4,
                                                           int* __restrict__ aggslot, int nb,
                                                           int xc4) {
    int i = blockIdx.x * 256 + threadIdx.x;
    if (i < n4) counts4[i] = make_int4(0, 0, 0, 0);
    if (i < nb) aggslot[i] = -1;
    if (i < xc4) {
        float4 v = x[i];
        x16[i] = make_uint2(pack_h2(v.x, v.y), pack_h2(v.z, v.w));
    }
}

__global__ void count_edges_kernel(const int* __restrict__ col, int* __restrict__ counts, int E) {
    int e = blockIdx.x * blockDim.x + threadIdx.x;
    if (e < E) atomicAdd(&counts[col[e]], 1);
}

// Single-launch scan (lookback): publish aggregate, then poll predecessors.
__global__ __launch_bounds__(256) void scan_fused_kernel(const int* __restrict__ counts,
                                                         int* __restrict__ aggslot,
                                                         int* __restrict__ offsets,
                                                         int* __restrict__ cursor,
                                                         float* __restrict__ dinv, int n) {
    int b = blockIdx.x;
    int tid = threadIdx.x;
    int lane = tid & 63, wid = tid >> 6;
    int i = b * 256 + tid;
    int c = (i < n) ? counts[i] : 0;

    int s = c;
    #pragma unroll
    for (int d = 1; d < 64; d <<= 1) {
        int u = __shfl_up(s, d);
        if (lane >= d) s += u;
    }
    __shared__ int ws[4];
    if (lane == 63) ws[wid] = s;
    __syncthreads();
    int add = 0;
    for (int w = 0; w < wid; ++w) add += ws[w];
    int incl = s + add;
    int blocktotal = ws[0] + ws[1] + ws[2] + ws[3];
    __syncthreads();

    if (tid == 0) atomicExch(&aggslot[b], blocktotal);

    int pre = 0;
    for (int t = tid; t < b; t += 256) {
        int a;
        do { a = atomicAdd(&aggslot[t], 0); } while (a < 0);
        pre += a;
    }
    #pragma unroll
    for (int d = 1; d < 64; d <<= 1) pre += __shfl_xor(pre, d);
    if (lane == 0) ws[wid] = pre;
    __syncthreads();
    int blockoff = ws[0] + ws[1] + ws[2] + ws[3];

    if (i < n) {
        offsets[i] = blockoff + incl - c;
        cursor[i] = 0;
        dinv[i] = rsqrtf((float)(c + 1));      // +1 self loop
    }
    if (i == n - 1) offsets[n] = blockoff + incl;
}

// GEMM tile body: 64 rows x DO cols, fdot2, f32 acc, dinv-scaled f16 store.
template <int DO>
__device__ __forceinline__ void gemm_tile_body(int tileb,
                                               const __half* __restrict__ A,
                                               const float* __restrict__ W,
                                               const float* __restrict__ dinv,
                                               __half* __restrict__ out, int n,
                                               h2* Wl) {
    constexpr int K = 128;
    constexpr int COLTH = DO / 8;          // 16 (DO=128) or 8 (DO=64)
    constexpr int ROWTH = 256 / COLTH;     // 16 or 32
    constexpr int R = 64 / ROWTH;          // 4 (DO=128) or 2 (DO=64)
    constexpr int BR = ROWTH * R;          // 64 rows per block
    constexpr int HALF = DO / 2;

    int tid = threadIdx.x;
    for (int idx = tid; idx < (K / 2) * (DO / 4); idx += 256) {
        int k2 = idx / (DO / 4);
        int c4 = idx % (DO / 4);
        float4 w0 = ((const float4*)(W + (size_t)(2 * k2) * DO))[c4];
        float4 w1 = ((const float4*)(W + (size_t)(2 * k2 + 1) * DO))[c4];
        h2* dst = &Wl[k2 * DO + c4 * 4];
        h2 d0; d0.x = (_Float16)w0.x; d0.y = (_Float16)w1.x; dst[0] = d0;
        h2 d1; d1.x = (_Float16)w0.y; d1.y = (_Float16)w1.y; dst[1] = d1;
        h2 d2; d2.x = (_Float16)w0.z; d2.y = (_Float16)w1.z; dst[2] = d2;
        h2 d3; d3.x = (_Float16)w0.w; d3.y = (_Float16)w1.w; dst[3] = d3;
    }
    __syncthreads();

    int ct = tid % COLTH;
    int rt = tid / COLTH;
    int rb = tileb * BR + rt * R;

    int rowc[R];
    #pragma unroll
    for (int i = 0; i < R; ++i) {
        int row = rb + i;
        rowc[i] = (row < n) ? row : (n - 1);
    }

    float acc[R][8];
    #pragma unroll
    for (int i = 0; i < R; ++i)
        #pragma unroll
        for (int c = 0; c < 8; ++c) acc[i][c] = 0.f;

    #pragma unroll 2
    for (int k8 = 0; k8 < K / 8; ++k8) {
        h8 av[R];
        #pragma unroll
        for (int i = 0; i < R; ++i) {
            av[i] = ((const h8*)(A + (size_t)rowc[i] * K))[k8];
        }
        #pragma unroll
        for (int kk = 0; kk < 4; ++kk) {
            int k2 = k8 * 4 + kk;
            h2 w0[4], w1[4];
            *(uint4*)w0 = *(const uint4*)(&Wl[k2 * DO + ct * 4]);
            *(uint4*)w1 = *(const uint4*)(&Wl[k2 * DO + HALF + ct * 4]);
            #pragma unroll
            for (int i = 0; i < R; ++i) {
                h2 a; a.x = av[i][2 * kk]; a.y = av[i][2 * kk + 1];
                #pragma unroll
                for (int c = 0; c < 4; ++c) {
                    acc[i][c]     = __builtin_amdgcn_fdot2(a, w0[c], acc[i][c], false);
                    acc[i][4 + c] = __builtin_amdgcn_fdot2(a, w1[c], acc[i][4 + c], false);
                }
            }
        }
    }

    #pragma unroll
    for (int i = 0; i < R; ++i) {
        int row = rb + i;
        if (row < n) {
            float dv = dinv[row];
            uint2 q0 = make_uint2(pack_h2(acc[i][0] * dv, acc[i][1] * dv),
                                  pack_h2(acc[i][2] * dv, acc[i][3] * dv));
            uint2 q1 = make_uint2(pack_h2(acc[i][4] * dv, acc[i][5] * dv),
                                  pack_h2(acc[i][6] * dv, acc[i][7] * dv));
            *(uint2*)(out + (size_t)row * DO + ct * 4) = q0;
            *(uint2*)(out + (size_t)row * DO + HALF + ct * 4) = q1;
        }
    }
}

// Plain GEMM kernel (layers 2/3).
template <int DO>
__global__ __launch_bounds__(256) void gemm16_kernel(const __half* __restrict__ A,
                                                     const float* __restrict__ W,
                                                     const float* __restrict__ dinv,
                                                     __half* __restrict__ out, int n) {
    constexpr int K = 128;
    __shared__ alignas(16) h2 Wl[(K / 2) * DO];
    gemm_tile_body<DO>(blockIdx.x, A, W, dinv, out, n, Wl);
}

// Range-split fill_csr (blocks [0,FB)) + layer-1 GEMM (blocks [FB, FB+GB)).
__global__ __launch_bounds__(256) void fill_gemm1_kernel(const int* __restrict__ row,
                                                         const int* __restrict__ col,
                                                         const int* __restrict__ offsets,
                                                         int* __restrict__ cursor,
                                                         int* __restrict__ srcs, int E, int FB,
                                                         const __half* __restrict__ A,
                                                         const float* __restrict__ W,
                                                         const float* __restrict__ dinv,
                                                         __half* __restrict__ out, int n) {
    __shared__ alignas(16) h2 Wl[64 * 128];   // 32 KB (DO=128 geometry)
    int b = blockIdx.x;
    if (b < FB) {
        int e = b * 256 + threadIdx.x;
        if (e < E) {
            int c = col[e];
            int pos = offsets[c] + atomicAdd(&cursor[c], 1);
            srcs[pos] = row[e];
        }
    } else {
        gemm_tile_body<128>(b - FB, A, W, dinv, out, n, Wl);
    }
}

// out[d] = bias + dinv[d] * (hw_s[d] + sum_e hw_s[src(e)])   (f32 acc)
// TPD = DO/4 lanes/dest, 8B f16 gathers, srcs loads software-pipelined.
template <int DO, bool RELU, bool F16OUT>
__global__ __launch_bounds__(256) void agg_kernel(const __half* __restrict__ hw,
                                                  const int* __restrict__ offsets,
                                                  const int* __restrict__ srcs,
                                                  const float* __restrict__ dinv,
                                                  const float* __restrict__ bias,
                                                  void* __restrict__ outp, int n) {
    constexpr int TPD = DO / 4;            // lanes per dest
    constexpr int DPB = 256 / TPD;         // dests per block
    int d = blockIdx.x * DPB + threadIdx.x / TPD;
    int j = threadIdx.x % TPD;             // 4-col chunk index
    if (d >= n) return;

    const float2* hw2 = (const float2*)hw; // 4 halves per unit
    int beg = offsets[d];
    int end = offsets[d + 1];

    float4 acc = h4_to_f4(hw2[(size_t)d * TPD + j]);   // self term (pre-scaled)

    int e = beg;
    if (e + 8 <= end) {
        int cs[8];
        #pragma unroll
        for (int k = 0; k < 8; ++k) cs[k] = srcs[e + k];
        while (true) {
            float2 g[8];
            #pragma unroll
            for (int k = 0; k < 8; ++k) g[k] = hw2[(size_t)cs[k] * TPD + j];
            e += 8;
            bool more = (e + 8 <= end);
            int nx[8];
            if (more) {
                #pragma unroll
                for (int k = 0; k < 8; ++k) nx[k] = srcs[e + k];
            }
            #pragma unroll
            for (int k = 0; k < 8; ++k) {
                float4 f = h4_to_f4(g[k]);
                acc.x += f.x; acc.y += f.y; acc.z += f.z; acc.w += f.w;
            }
            if (!more) break;
            #pragma unroll
            for (int k = 0; k < 8; ++k) cs[k] = nx[k];
        }
    }
    for (; e + 4 <= end; e += 4) {
        int s0 = srcs[e + 0], s1 = srcs[e + 1], s2 = srcs[e + 2], s3 = srcs[e + 3];
        float4 v0 = h4_to_f4(hw2[(size_t)s0 * TPD + j]);
        float4 v1 = h4_to_f4(hw2[(size_t)s1 * TPD + j]);
        float4 v2 = h4_to_f4(hw2[(size_t)s2 * TPD + j]);
        float4 v3 = h4_to_f4(hw2[(size_t)s3 * TPD + j]);
        acc.x += v0.x; acc.y += v0.y; acc.z += v0.z; acc.w += v0.w;
        acc.x += v1.x; acc.y += v1.y; acc.z += v1.z; acc.w += v1.w;
        acc.x += v2.x; acc.y += v2.y; acc.z += v2.z; acc.w += v2.w;
        acc.x += v3.x; acc.y += v3.y; acc.z += v3.z; acc.w += v3.w;
    }
    for (; e < end; ++e) {
        float4 v = h4_to_f4(hw2[(size_t)srcs[e] * TPD + j]);
        acc.x += v.x; acc.y += v.y; acc.z += v.z; acc.w += v.w;
    }

    float di = dinv[d];
    float4 b4 = ((const float4*)bias)[j];
    acc.x = b4.x + di * acc.x;
    acc.y = b4.y + di * acc.y;
    acc.z = b4.z + di * acc.z;
    acc.w = b4.w + di * acc.w;

    if (RELU) {
        acc.x = fmaxf(acc.x, 0.f); acc.y = fmaxf(acc.y, 0.f);
        acc.z = fmaxf(acc.z, 0.f); acc.w = fmaxf(acc.w, 0.f);
    }
    if (F16OUT) {
        uint2 q = make_uint2(pack_h2(acc.x, acc.y), pack_h2(acc.z, acc.w));
        ((uint2*)outp)[(size_t)d * TPD + j] = q;
    } else {
        ((float4*)outp)[(size_t)d * TPD + j] = acc;
    }
}

extern "C" void kernel_launch(void* const* d_in, const int* in_sizes, int n_in,
                              void* d_out, int out_size, void* d_ws, size_t ws_size,
                              hipStream_t stream) {
    const float* x  = (const float*)d_in[0];
    const float* W1 = (const float*)d_in[1];
    const float* b1 = (const float*)d_in[2];
    const float* W2 = (const float*)d_in[3];
    const float* b2 = (const float*)d_in[4];
    const float* W3 = (const float*)d_in[5];
    const float* b3 = (const float*)d_in[6];
    const int*   ei = (const int*)d_in[7];

    const int N = in_sizes[0] / 128;
    const int E = in_sizes[7] / 2;
    const int* rowi = ei;       // edge_index[0] = sources
    const int* coli = ei + E;   // edge_index[1] = targets

    float* out = (float*)d_out;

    // workspace carve-up (256B aligned)
    char* ws = (char*)d_ws;
    size_t off = 0;
    auto alloc = [&](size_t bytes) -> void* {
        void* p = ws + off;
        off = (off + bytes + 255) & ~(size_t)255;
        return p;
    };
    const int NB = (N + 255) / 256;        // scan blocks (196 for N=50000)
    float* dinv     = (float*)alloc((size_t)N * 4);
    int*   counts   = (int*)  alloc(((size_t)N + 4) * 4);  // int4-padded
    int*   offsets  = (int*)  alloc((size_t)(N + 1) * 4);
    int*   cursor   = (int*)  alloc((size_t)N * 4);
    int*   aggslot  = (int*)  alloc((size_t)NB * 4);
    int*   srcs     = (int*)  alloc((size_t)E * 4);
    __half* x16     = (__half*)alloc((size_t)N * 128 * 2);
    __half* hw16    = (__half*)alloc((size_t)N * 128 * 2);
    __half* h16     = (__half*)alloc((size_t)N * 128 * 2);

    // ---- fused prelude: zero counts + init slots + x->f16 ----
    const int n4 = (N + 3) / 4;
    const int xc4 = N * 128 / 4;
    prelude_init_kernel<<<(xc4 + 255) / 256, 256, 0, stream>>>(
        (const float4*)x, (uint2*)x16, (int4*)counts, n4, aggslot, NB, xc4);
    count_edges_kernel<<<(E + 255) / 256, 256, 0, stream>>>(coli, counts, E);
    scan_fused_kernel<<<NB, 256, 0, stream>>>(counts, aggslot, offsets, cursor, dinv, N);

    // ---- fused fill_csr + layer-1 GEMM (range-split) ----
    const int FB = (E + 255) / 256;            // fill blocks (2344)
    const int GB = (N + 63) / 64;              // gemm tiles (782)
    fill_gemm1_kernel<<<FB + GB, 256, 0, stream>>>(rowi, coli, offsets, cursor, srcs, E, FB,
                                                   x16, W1, dinv, hw16, N);
    agg_kernel<128, true, true><<<(N + 7) / 8, 256, 0, stream>>>(hw16, offsets, srcs, dinv, b1, h16, N);

    // ---- layer 2 ----
    gemm16_kernel<128><<<(N + 63) / 64, 256, 0, stream>>>(h16, W2, dinv, hw16, N);
    agg_kernel<128, true, true><<<(N + 7) / 8, 256, 0, stream>>>(hw16, offsets, srcs, dinv, b2, h16, N);

    // ---- layer 3 (no relu), width 64, f32 out ----
    gemm16_kernel<64><<<(N + 63) / 64, 256, 0, stream>>>(h16, W3, dinv, hw16, N);
    agg_kernel<64, false, false><<<(N + 15) / 16, 256, 0, stream>>>(hw16, offsets, srcs, dinv, b3, out, N);
}